// Round 1
// baseline (655.436 us; speedup 1.0000x reference)
//
#include <hip/hip_runtime.h>
#include <stdint.h>

#define CAP 128   // max nnz per normalized-adj row (Poisson(41): P(>=128) ~ 1e-26)
#define RPB 4     // rows per block in spmm (1 wave each, half-row per wave)

typedef __attribute__((ext_vector_type(8))) short bf16x8;
typedef __attribute__((ext_vector_type(4))) float f32x4;
typedef __attribute__((ext_vector_type(4))) uint32_t u32x4;
typedef __attribute__((ext_vector_type(2))) uint32_t u32x2;

typedef __attribute__((address_space(3))) uint32_t lds_u32;
typedef __attribute__((address_space(1))) const uint32_t glb_u32;

__device__ __forceinline__ unsigned short f2bf(float f) {
  union { float f; uint32_t u; } c; c.f = f;
  return (unsigned short)((c.u + 0x7fffu + ((c.u >> 16) & 1u)) >> 16);
}
__device__ __forceinline__ float bf2f(uint32_t b) {
  union { uint32_t u; float f; } c; c.u = b << 16; return c.f;
}
__device__ __forceinline__ float as_f32(uint32_t u) {
  union { uint32_t u; float f; } c; c.u = u; return c.f;
}

// ---------- dtype detection ----------
// f32 adjacency words are only 0x00000000 / 0x3F800000. bf16-pair words
// (1.0,0.0)=0x00003F80 and (1.0,1.0)=0x3F803F80 cannot occur in f32 data.
__global__ __launch_bounds__(256) void k_detect(const uint32_t* __restrict__ a,
                                                int* __restrict__ flag) {
  int i = blockIdx.x * 256 + threadIdx.x;   // 65536 threads
  bool found = false;
  for (int k = 0; k < 64; k++) {
    uint32_t x = __builtin_nontemporal_load(&a[(size_t)k * 65536 + i]);
    if (x == 0x00003F80u || x == 0x3F803F80u) found = true;
  }
  if (found) flag[0] = 1;   // benign same-value race
}

// ---------- CSR build ----------
__global__ __launch_bounds__(256) void k_build(const void* __restrict__ adjp,
                                               int* __restrict__ cnt,
                                               int* __restrict__ cols,
                                               const int* __restrict__ flag) {
  int gid = blockIdx.x * 256 + threadIdx.x;   // 32768 blocks -> 8388608 threads
  if (flag[0]) {
    const u32x4* a = (const u32x4*)adjp;
    u32x4 v = __builtin_nontemporal_load(&a[gid]);
    int i0 = (gid & 511) * 8;
    int j  = (gid >> 9) & 4095;
    int b  = gid >> 21;
    int base = b << 12;
    uint32_t w[4] = {v[0], v[1], v[2], v[3]};
#pragma unroll
    for (int q = 0; q < 4; q++) {
      if (w[q] & 0xffffu) {
        int c = base + i0 + q * 2;
        int p = atomicAdd(&cnt[c], 1);
        if (p < CAP) cols[(size_t)c * CAP + p] = j;
      }
      if (w[q] >> 16) {
        int c = base + i0 + q * 2 + 1;
        int p = atomicAdd(&cnt[c], 1);
        if (p < CAP) cols[(size_t)c * CAP + p] = j;
      }
    }
  } else {
    const f32x4* a = (const f32x4*)adjp;
#pragma unroll
    for (int it = 0; it < 2; it++) {
      int v4 = gid + it * 8388608;
      f32x4 v = __builtin_nontemporal_load(&a[v4]);
      int i0 = (v4 & 1023) * 4;
      int j  = (v4 >> 10) & 4095;
      int b  = v4 >> 22;
      int base = b << 12;
      float e[4] = {v[0], v[1], v[2], v[3]};
#pragma unroll
      for (int q = 0; q < 4; q++) {
        if (e[q] != 0.0f) {
          int c = base + i0 + q;
          int p = atomicAdd(&cnt[c], 1);
          if (p < CAP) cols[(size_t)c * CAP + p] = j;
        }
      }
    }
  }
}

// ---------- dinv + bias conversion (merged) ----------
__global__ __launch_bounds__(256) void k_prep(const int* __restrict__ cnt,
                                              float* __restrict__ dinv,
                                              const void* b1, const void* b2,
                                              const void* b3,
                                              float* __restrict__ b1f,
                                              float* __restrict__ b2f,
                                              float* __restrict__ b3f,
                                              const int* __restrict__ flag) {
  int id = blockIdx.x * 256 + threadIdx.x;  // 70 blocks = 17920 threads
  if (id < 16384) {
    int c = cnt[id];
    dinv[id] = (c > 0) ? 1.0f / sqrtf((float)c) : 0.0f;
  } else {
    int o = id - 16384;
    if (o < 1536) {
      const void* src = (o < 512) ? b1 : (o < 1024) ? b2 : b3;
      float* dst = (o < 512) ? b1f : (o < 1024) ? b2f : b3f;
      int i = o & 511;
      dst[i] = flag[0] ? bf2f(((const ushort*)src)[i]) : ((const float*)src)[i];
    }
  }
}

// ---------- X conversion ----------
__global__ __launch_bounds__(256) void k_convx(const void* __restrict__ xp,
                                               ushort* __restrict__ xb,
                                               const int* __restrict__ flag) {
  int gid = blockIdx.x * 256 + threadIdx.x;  // 1048576
  if (flag[0]) {
    const u32x4* in = (const u32x4*)xp;
    u32x4 v = __builtin_nontemporal_load(&in[gid]);
    ((u32x4*)xb)[gid] = v;
  } else {
    const f32x4* in = (const f32x4*)xp;
#pragma unroll
    for (int it = 0; it < 2; it++) {
      int i = gid + it * 1048576;
      f32x4 v = __builtin_nontemporal_load(&in[i]);
      uint32_t lo = (uint32_t)f2bf(v[0]) | ((uint32_t)f2bf(v[1]) << 16);
      uint32_t hi = (uint32_t)f2bf(v[2]) | ((uint32_t)f2bf(v[3]) << 16);
      ((uint2*)xb)[i] = make_uint2(lo, hi);
    }
  }
}

// ---------- all 3 weights transposed+converted in one launch ----------
__global__ __launch_bounds__(256) void k_wconv(const void* w1, const void* w2,
                                               const void* w3,
                                               ushort* __restrict__ wt1,
                                               ushort* __restrict__ wt2,
                                               ushort* __restrict__ wt3,
                                               const int* __restrict__ flag) {
  int id = blockIdx.x * 256 + threadIdx.x;   // 3072 blocks
  int w = id >> 18;                          // 262144 elems each
  int o = id & 262143;
  const void* wp = (w == 0) ? w1 : (w == 1) ? w2 : w3;
  ushort* wt = (w == 0) ? wt1 : (w == 1) ? wt2 : wt3;
  int n = o >> 9, k = o & 511;
  if (flag[0]) wt[o] = ((const ushort*)wp)[k * 512 + n];
  else         wt[o] = f2bf(((const float*)wp)[k * 512 + n]);
}

// ---------- bf16 MFMA GEMM: Z[M,512] = X[M,512] @ W  (WT is [n][k]) ----------
// Block->XCD remap so the Z slice for (batch b, col-half h) is WRITTEN on
// XCD 2b+h — the exact XCD the following k_spmm READS it from. Z lines are
// dirty-resident in that L2 when spmm launches.
__device__ __forceinline__ void gl_lds16(const ushort* g, ushort* l) {
  __builtin_amdgcn_global_load_lds((glb_u32*)g, (lds_u32*)l, 16, 0, 0);
}

__global__ __launch_bounds__(256) void k_gemm(const ushort* __restrict__ X,
                                              const ushort* __restrict__ WT,
                                              ushort* __restrict__ Z) {
  __shared__ ushort As[128 * 32];
  __shared__ ushort Bs[128 * 32];
  const int K = 512, NO = 512;
  int tid = threadIdx.x;
  // 512 blocks 1D. XCD = linear%8 (round-robin). xcd -> (batch, col-half).
  int l = blockIdx.x;
  int xcd = l & 7, idx = l >> 3;              // idx in [0,64)
  int mt = ((xcd >> 1) << 5) + (idx >> 1);    // m-tile [0,128): batch*32 + ...
  int ntile = ((xcd & 1) << 1) + (idx & 1);   // n-tile [0,4): half*2 + ...
  int m0 = mt << 7, n0 = ntile << 7;
  int lane = tid & 63;
  int wv = tid >> 6;
  int wm = (wv >> 1) << 6;
  int wn = (wv & 1) << 6;
  int lr = lane & 15;
  int lq = lane >> 4;

  f32x4 zero = {0.f, 0.f, 0.f, 0.f};
  f32x4 acc[4][4];
#pragma unroll
  for (int im = 0; im < 4; im++)
#pragma unroll
    for (int in_ = 0; in_ < 4; in_++) acc[im][in_] = zero;

  const ushort* Xg = X  + (size_t)(m0 + (tid >> 2)) * K + ((tid & 3) << 3);
  const ushort* Wg = WT + (size_t)(n0 + (tid >> 2)) * K + ((tid & 3) << 3);

  for (int kt = 0; kt < K; kt += 32) {
    __syncthreads();
    gl_lds16(Xg + kt,                    &As[tid * 8]);
    gl_lds16(Xg + kt + (size_t)64 * K,   &As[2048 + tid * 8]);
    gl_lds16(Wg + kt,                    &Bs[tid * 8]);
    gl_lds16(Wg + kt + (size_t)64 * K,   &Bs[2048 + tid * 8]);
    __syncthreads();
    bf16x8 af[4], bfr[4];
#pragma unroll
    for (int im = 0; im < 4; im++)
      af[im] = *(const bf16x8*)&As[(wm + im * 16 + lr) * 32 + lq * 8];
#pragma unroll
    for (int in_ = 0; in_ < 4; in_++)
      bfr[in_] = *(const bf16x8*)&Bs[(wn + in_ * 16 + lr) * 32 + lq * 8];
#pragma unroll
    for (int im = 0; im < 4; im++)
#pragma unroll
      for (int in_ = 0; in_ < 4; in_++)
        acc[im][in_] = __builtin_amdgcn_mfma_f32_16x16x32_bf16(
            af[im], bfr[in_], acc[im][in_], 0, 0, 0);
  }

#pragma unroll
  for (int im = 0; im < 4; im++) {
    int row0 = m0 + wm + im * 16 + lq * 4;
#pragma unroll
    for (int in_ = 0; in_ < 4; in_++) {
      int col = n0 + wn + in_ * 16 + lr;
#pragma unroll
      for (int r = 0; r < 4; r++)
        Z[(size_t)(row0 + r) * NO + col] = f2bf(acc[im][in_][r]);
    }
  }
}

// ---------- SpMM: out[r,:] = sum_j d_r*d_j * Z[j,:] (+bias, relu) ----------
// Column-split: each wave owns one (row, col-half). XCD = block%8 ->
// (batch, half), so per-XCD Z working set is 2 MB (half of the 4 MB batch
// slice) and matches the GEMM's write XCD. Output/cols are non-temporal so
// they don't evict the Z-resident lines.
__global__ __launch_bounds__(256) void k_spmm(const ushort* __restrict__ Z,
                                              const int* __restrict__ cnt,
                                              const int* __restrict__ cols,
                                              const float* __restrict__ dinv,
                                              const float* __restrict__ bias,
                                              void* __restrict__ outp,
                                              int do_relu, int is_final,
                                              const int* __restrict__ flag) {
  __shared__ int   sj[RPB][CAP];
  __shared__ float sv[RPB][CAP];
  int Bk = blockIdx.x;                 // 8192 blocks
  int wv = threadIdx.x >> 6;
  int lane = threadIdx.x & 63;
  int batch = (Bk & 7) >> 1;           // XCD pair -> batch
  int half  = Bk & 1;                  // XCD parity -> column half
  int lb    = Bk >> 3;                 // [0,1024)
  int r = (batch << 12) + lb * RPB + wv;
  int base = batch << 12;

  int nnz = cnt[r];
  if (nnz > CAP) nnz = CAP;
  float dr = dinv[r];
  for (int k = lane; k < nnz; k += 64) {        // <=2 iterations (CAP=128)
    int j = __builtin_nontemporal_load(&cols[(size_t)r * CAP + k]);
    sj[wv][k] = j;
    sv[wv][k] = dr * dinv[base + j];
  }
  // wave-local LDS producer/consumer: lgkmcnt ordering within the wave

  int c0 = (half << 8) + (lane << 2);           // 4 ushorts per lane
  const ushort* Zb = Z + (size_t)base * 512 + c0;
  f32x4 bb = *(const f32x4*)(bias + c0);
  float a0 = bb[0], a1 = bb[1], a2 = bb[2], a3 = bb[3];

  int k = 0;
  for (; k + 2 <= nnz; k += 2) {
    int j0 = sj[wv][k], j1 = sj[wv][k + 1];
    float v0 = sv[wv][k], v1 = sv[wv][k + 1];
    u32x2 z0 = *(const u32x2*)(Zb + (size_t)j0 * 512);
    u32x2 z1 = *(const u32x2*)(Zb + (size_t)j1 * 512);
    a0 += v0 * as_f32(z0[0] << 16); a1 += v0 * as_f32(z0[0] & 0xffff0000u);
    a2 += v0 * as_f32(z0[1] << 16); a3 += v0 * as_f32(z0[1] & 0xffff0000u);
    a0 += v1 * as_f32(z1[0] << 16); a1 += v1 * as_f32(z1[0] & 0xffff0000u);
    a2 += v1 * as_f32(z1[1] << 16); a3 += v1 * as_f32(z1[1] & 0xffff0000u);
  }
  if (k < nnz) {
    int j0 = sj[wv][k];
    float v0 = sv[wv][k];
    u32x2 z0 = *(const u32x2*)(Zb + (size_t)j0 * 512);
    a0 += v0 * as_f32(z0[0] << 16); a1 += v0 * as_f32(z0[0] & 0xffff0000u);
    a2 += v0 * as_f32(z0[1] << 16); a3 += v0 * as_f32(z0[1] & 0xffff0000u);
  }

  if (do_relu) {
    a0 = fmaxf(a0, 0.f); a1 = fmaxf(a1, 0.f);
    a2 = fmaxf(a2, 0.f); a3 = fmaxf(a3, 0.f);
  }

  if (!is_final || flag[0]) {
    u32x2 o;
    o[0] = (uint32_t)f2bf(a0) | ((uint32_t)f2bf(a1) << 16);
    o[1] = (uint32_t)f2bf(a2) | ((uint32_t)f2bf(a3) << 16);
    __builtin_nontemporal_store(o, (u32x2*)((ushort*)outp + (size_t)r * 512 + c0));
  } else {
    f32x4 o = {a0, a1, a2, a3};
    __builtin_nontemporal_store(o, (f32x4*)((float*)outp + (size_t)r * 512 + c0));
  }
}

extern "C" void kernel_launch(void* const* d_in, const int* in_sizes, int n_in,
                              void* d_out, int out_size, void* d_ws, size_t ws_size,
                              hipStream_t stream) {
  const void* X  = d_in[0];
  const void* A  = d_in[1];
  const void* W1 = d_in[2]; const void* b1 = d_in[3];
  const void* W2 = d_in[4]; const void* b2 = d_in[5];
  const void* W3 = d_in[6]; const void* b3 = d_in[7];

  char* ws = (char*)d_ws;
  size_t off = 0;
  auto alloc = [&](size_t bytes) -> void* {
    void* p = ws + off;
    off += (bytes + 255) & ~(size_t)255;
    return p;
  };
  int*    cnt  = (int*)alloc(16384 * 4);
  int*    flag = (int*)alloc(4);
  float*  dinv = (float*)alloc(16384 * 4);
  int*    cols = (int*)alloc((size_t)16384 * CAP * 4);
  ushort* W1T  = (ushort*)alloc(512 * 512 * 2);
  ushort* W2T  = (ushort*)alloc(512 * 512 * 2);
  ushort* W3T  = (ushort*)alloc(512 * 512 * 2);
  float*  b1f  = (float*)alloc(512 * 4);
  float*  b2f  = (float*)alloc(512 * 4);
  float*  b3f  = (float*)alloc(512 * 4);
  ushort* Xb   = (ushort*)alloc((size_t)16384 * 512 * 2);
  ushort* Zb   = (ushort*)alloc((size_t)16384 * 512 * 2);
  ushort* Hb   = (ushort*)alloc((size_t)16384 * 512 * 2);

  hipMemsetAsync(cnt, 0, 65536 + 256, stream);   // cnt + flag

  k_detect<<<256, 256, 0, stream>>>((const uint32_t*)A, flag);
  k_build<<<32768, 256, 0, stream>>>(A, cnt, cols, flag);
  k_prep<<<70, 256, 0, stream>>>(cnt, dinv, b1, b2, b3, b1f, b2f, b3f, flag);
  k_convx<<<4096, 256, 0, stream>>>(X, Xb, flag);
  k_wconv<<<3072, 256, 0, stream>>>(W1, W2, W3, W1T, W2T, W3T, flag);

  k_gemm<<<512, 256, 0, stream>>>(Xb, W1T, Zb);
  k_spmm<<<8192, 256, 0, stream>>>(Zb, cnt, cols, dinv, b1f, Hb, 1, 0, flag);
  k_gemm<<<512, 256, 0, stream>>>(Hb, W2T, Zb);
  k_spmm<<<8192, 256, 0, stream>>>(Zb, cnt, cols, dinv, b2f, Xb, 1, 0, flag);
  k_gemm<<<512, 256, 0, stream>>>(Xb, W3T, Zb);
  k_spmm<<<8192, 256, 0, stream>>>(Zb, cnt, cols, dinv, b3f, d_out, 0, 1, flag);
}